// Round 3
// baseline (364.291 us; speedup 1.0000x reference)
//
#include <hip/hip_runtime.h>
#include <math.h>

typedef unsigned short u16;
typedef unsigned int u32;

#define B_   256
#define F_   512
#define T_   81
#define WIN_ 1022
#define HOP_ 400
#define NF_  69
#define OUT_LEN_ 28550
#define SEG_ 1000
#define OVL_ 50

#define MA_  20736     // B_*T_
#define MB_  17664     // B_*NF_
#define K_   1024
#define NMA_TILES 162  // MA_/128
#define NMB_TILES 138  // MB_/128
#define NMA_PAD   168  // next multiple of 8
#define NMB_PAD   144

// workspace byte offsets
#define SYNWIN_B   0u
#define HANN_B     4096u
#define BASA_B     8192u                      // 1024*1024 bf16 = 2 MiB
#define BASB_B     (BASA_B + 2097152u)
#define ABUF_B     (BASB_B + 2097152u)        // 20736*1024 bf16
#define TF_B       (ABUF_B + 42467328u)       // 20736*1024 bf16
#define OUTF_B     (TF_B + 42467328u)         // 256*28672 bf16
#define OUTF_STRIDE_ 28672

typedef __attribute__((ext_vector_type(8))) short bf8_t;
typedef __attribute__((ext_vector_type(4))) float f4_t;
typedef const __attribute__((address_space(1))) void* as1cv;
typedef __attribute__((address_space(3))) void* as3v;

__device__ __forceinline__ float b2f(u16 v) {
  u32 u = ((u32)v) << 16; float f; __builtin_memcpy(&f, &u, 4); return f;
}
__device__ __forceinline__ u16 f2b(float f) {
  u32 u; __builtin_memcpy(&u, &f, 4);
  return (u16)((u + 0x7fffu + ((u >> 16) & 1u)) >> 16);
}

// ---------------------------------------------------------------------------
// K1: synthesis window + hann tables
// ---------------------------------------------------------------------------
__global__ __launch_bounds__(256) void k1_tables(float* __restrict__ ws) {
  int i = blockIdx.x * 256 + threadIdx.x;
  if (i >= WIN_) return;
  const float twopi_N = 6.283185307179586f / (float)WIN_;
  float w = 0.5f - 0.5f * cosf(twopi_N * (float)i);
  int j = i % HOP_;
  float a = 0.5f - 0.5f * cosf(twopi_N * (float)j);
  float b = 0.5f - 0.5f * cosf(twopi_N * (float)(j + 400));
  float d = a * a + b * b;
  if (j + 800 < WIN_) {
    float c = 0.5f - 0.5f * cosf(twopi_N * (float)(j + 800));
    d += c * c;
  }
  ((float*)((char*)ws + SYNWIN_B))[i] = w / d;
  ((float*)((char*)ws + HANN_B))[i]   = w;
}

// ---------------------------------------------------------------------------
// BasisA[n][2k+j]: iDFT basis, transposed (n-major), synwin/N and c_k folded.
// ---------------------------------------------------------------------------
__global__ __launch_bounds__(256) void gen_basisA(const float* __restrict__ synwin,
                                                  u16* __restrict__ BA) {
  int n = blockIdx.x;                 // 0..1023
  float scale = (n < WIN_) ? synwin[n] * (1.0f / (float)WIN_) : 0.f;
  for (int k = threadIdx.x; k < 512; k += 256) {
    int m = (k * n) % WIN_;
    float ang = 6.283185307179586f * (float)m / (float)WIN_;
    float s, c; __sincosf(ang, &s, &c);
    bool edge = (k == 0) || (k == 511);
    float ck = edge ? 1.f : 2.f;
    float re = scale * ck * c;
    float im = edge ? 0.f : -scale * ck * s;
    BA[(size_t)n * K_ + 2 * k]     = f2b(re);
    BA[(size_t)n * K_ + 2 * k + 1] = f2b(im);
  }
}

// ---------------------------------------------------------------------------
// BasisB[2k+j][w]: forward DFT basis, transposed, hann folded in; 0 for w>=1022
// so GEMM B can read its A-operand straight from outf (incl. 2 garbage cols).
// ---------------------------------------------------------------------------
__global__ __launch_bounds__(256) void gen_basisB(const float* __restrict__ hann,
                                                  u16* __restrict__ BB) {
  int k = blockIdx.x;                 // 0..511
  for (int w = threadIdx.x; w < K_; w += 256) {
    float re = 0.f, im = 0.f;
    if (w < WIN_) {
      int m = (k * w) % WIN_;
      float ang = 6.283185307179586f * (float)m / (float)WIN_;
      float s, c; __sincosf(ang, &s, &c);
      float h = hann[w];
      re = h * c; im = -h * s;
    }
    BB[(size_t)(2 * k)     * K_ + w] = f2b(re);
    BB[(size_t)(2 * k + 1) * K_ + w] = f2b(im);
  }
}

// ---------------------------------------------------------------------------
// prep1: x[b][k][t][2] fp32 -> Abuf[b*81+t][2k+j] bf16 (LDS-tiled transpose)
// ---------------------------------------------------------------------------
__global__ __launch_bounds__(256) void prep1(const float* __restrict__ x,
                                             u16* __restrict__ Abuf) {
  __shared__ float2 tile[32][33];
  int k0 = blockIdx.x * 32, t0 = blockIdx.y * 32, b = blockIdx.z;
  int c = threadIdx.x & 31, rr = threadIdx.x >> 5;
  const float2* xp = (const float2*)x;
#pragma unroll
  for (int i = 0; i < 4; ++i) {
    int k = k0 + rr + 8 * i, t = t0 + c;
    float2 v = make_float2(0.f, 0.f);
    if (t < T_) v = xp[(size_t)(b * F_ + k) * T_ + t];
    tile[rr + 8 * i][c] = v;
  }
  __syncthreads();
#pragma unroll
  for (int i = 0; i < 4; ++i) {
    int t = t0 + rr + 8 * i, kc = c;
    if (t < T_) {
      float2 v = tile[kc][rr + 8 * i];
      u32 packed = (u32)f2b(v.x) | ((u32)f2b(v.y) << 16);
      *(u32*)&Abuf[(size_t)(b * T_ + t) * K_ + 2 * (k0 + kc)] = packed;
    }
  }
}

// ---------------------------------------------------------------------------
// GEMM: C[M x 1024] = A[M x 1024] * Bt[1024 x 1024]^T  (Bt stored n-major)
// 128x128 tile, 4 waves (2x2 of 64x64), mfma 16x16x32 bf16, BK=32.
// LDS layout is FRAGMENT-ORDERED: each 16x32 subtile stored so that lane l's
// MFMA fragment (row=l&15, kchunk=l>>4) is at byte offset l*16 -> both the
// global_load_lds staging write and the ds_read_b128 fragment read are
// perfectly sequential (zero bank conflicts).
// Grid is XCD-swizzled 1D: the 8 N-tiles of one M-strip land on one XCD.
// EPI 0: A from dense rows (stride K_), store bf16 C.
// EPI 1: A read directly from outf (row m=b*69+f at b*28672+f*400, stride
//        400; cols >=1022 garbage, zeroed by basis), float2 scatter to d_out.
// ---------------------------------------------------------------------------
template <int EPI>
__global__ __launch_bounds__(256) void gemm_bf16(const u16* __restrict__ A,
                                                 const u16* __restrict__ Bt,
                                                 void* __restrict__ Cout) {
  __shared__ u16 sA[8 * 512];
  __shared__ u16 sB[8 * 512];
  const int tid = threadIdx.x;
  const int lane = tid & 63, wv = tid >> 6;

  // XCD swizzle: id&7 = xcd; consecutive slots on an XCD sweep n for fixed m.
  int id = blockIdx.x;
  int xcd = id & 7, slot = id >> 3;
  int mt = (slot >> 3) * 8 + xcd;
  int nt = slot & 7;
  const int nM = (EPI == 0) ? NMA_TILES : NMB_TILES;
  if (mt >= nM) return;
  const int bm = mt * 128, bn = nt * 128;

  const int fr = lane & 15, fq = lane >> 4;
  const int s0 = 2 * wv, s1 = s0 + 1;

  const u16 *pA0, *pA1;
  if (EPI == 0) {
    pA0 = A + (size_t)(bm + 16 * s0 + fr) * K_ + fq * 8;
    pA1 = A + (size_t)(bm + 16 * s1 + fr) * K_ + fq * 8;
  } else {
    int m0 = bm + 16 * s0 + fr;
    int b0 = m0 / NF_, f0 = m0 - b0 * NF_;
    pA0 = A + (size_t)b0 * OUTF_STRIDE_ + f0 * HOP_ + fq * 8;
    int m1 = m0 + 16;
    int b1 = m1 / NF_, f1 = m1 - b1 * NF_;
    pA1 = A + (size_t)b1 * OUTF_STRIDE_ + f1 * HOP_ + fq * 8;
  }
  const u16* pB0 = Bt + (size_t)(bn + 16 * s0 + fr) * K_ + fq * 8;
  const u16* pB1 = Bt + (size_t)(bn + 16 * s1 + fr) * K_ + fq * 8;

  u16* lA0 = sA + s0 * 512;
  u16* lA1 = sA + s1 * 512;
  u16* lB0 = sB + s0 * 512;
  u16* lB1 = sB + s1 * 512;

  f4_t acc[4][4];
#pragma unroll
  for (int i = 0; i < 4; ++i)
#pragma unroll
    for (int j = 0; j < 4; ++j) acc[i][j] = (f4_t){0.f, 0.f, 0.f, 0.f};

  const int wm4 = (wv >> 1) * 4, wn4 = (wv & 1) * 4;   // subtile bases

  for (int k0 = 0; k0 < K_; k0 += 32) {
    __builtin_amdgcn_global_load_lds((as1cv)(const void*)(pA0 + k0), (as3v)lA0, 16, 0, 0);
    __builtin_amdgcn_global_load_lds((as1cv)(const void*)(pA1 + k0), (as3v)lA1, 16, 0, 0);
    __builtin_amdgcn_global_load_lds((as1cv)(const void*)(pB0 + k0), (as3v)lB0, 16, 0, 0);
    __builtin_amdgcn_global_load_lds((as1cv)(const void*)(pB1 + k0), (as3v)lB1, 16, 0, 0);
    __builtin_amdgcn_s_waitcnt(0x0f70);  // vmcnt(0)
    __syncthreads();

    bf8_t af[4], bq[4];
#pragma unroll
    for (int i = 0; i < 4; ++i)
      af[i] = *(const bf8_t*)&sA[(wm4 + i) * 512 + lane * 8];
#pragma unroll
    for (int j = 0; j < 4; ++j)
      bq[j] = *(const bf8_t*)&sB[(wn4 + j) * 512 + lane * 8];
#pragma unroll
    for (int i = 0; i < 4; ++i)
#pragma unroll
      for (int j = 0; j < 4; ++j)
        acc[i][j] = __builtin_amdgcn_mfma_f32_16x16x32_bf16(af[i], bq[j], acc[i][j], 0, 0, 0);
    __syncthreads();
  }

  const int wm = wm4 * 16, wn = wn4 * 16;
  if (EPI == 0) {
    u16* C = (u16*)Cout;
#pragma unroll
    for (int i = 0; i < 4; ++i)
#pragma unroll
      for (int j = 0; j < 4; ++j) {
        int colg = bn + wn + 16 * j + fr;
#pragma unroll
        for (int r = 0; r < 4; ++r) {
          int rowg = bm + wm + 16 * i + fq * 4 + r;
          C[(size_t)rowg * K_ + colg] = f2b(acc[i][j][r]);
        }
      }
  } else {
    // per-wave LDS repack -> coalesced float2 scatter into out[b][k][f][2]
    float* out = (float*)Cout;
    float* ep = ((wv & 2) ? (float*)sB : (float*)sA) + (wv & 1) * 1024;  // 64x16 f32
    for (int j = 0; j < 4; ++j) {
#pragma unroll
      for (int i = 0; i < 4; ++i)
#pragma unroll
        for (int r = 0; r < 4; ++r) {
          int row64 = 16 * i + fq * 4 + r;
          ep[row64 * 16 + fr] = acc[i][j][r];
        }
      __syncthreads();
      int m = bm + wm + lane;          // frame index
      int b = m / NF_;
      int f = m - b * NF_;
      int colbase = bn + wn + 16 * j;  // even
#pragma unroll
      for (int a = 0; a < 8; ++a) {
        int k = (colbase >> 1) + a;
        float2 v = make_float2(ep[lane * 16 + 2 * a], ep[lane * 16 + 2 * a + 1]);
        ((float2*)out)[((size_t)b * F_ + k) * NF_ + f] = v;
      }
      __syncthreads();
    }
  }
}

// ---------------------------------------------------------------------------
// fold: overlap-add gather + keep + crossfade (bf16 in / bf16 out)
// ---------------------------------------------------------------------------
__device__ __forceinline__ float sigval(const u16* __restrict__ tfb, int i) {
  int t1 = i / HOP_; if (t1 > T_ - 1) t1 = T_ - 1;
  int t0 = (i >= WIN_) ? (i - (WIN_ - 1) + HOP_ - 1) / HOP_ : 0;
  float acc = 0.f;
  for (int t = t0; t <= t1; ++t)
    acc += b2f(tfb[(size_t)t * K_ + (i - t * HOP_)]);
  return acc;
}

__global__ __launch_bounds__(256) void k3_fold(const u16* __restrict__ tf,
                                               u16* __restrict__ outf) {
  int id = blockIdx.x * 256 + threadIdx.x;
  if (id >= B_ * OUT_LEN_) return;
  int b = id / OUT_LEN_;
  int p = id - b * OUT_LEN_;
  int s, r;
  if (p < SEG_) { s = 0; r = p; }
  else {
    int q = p - SEG_;
    s = q / (SEG_ - OVL_) + 1;
    r = OVL_ + (q - (s - 1) * (SEG_ - OVL_));
  }
  const u16* tfb = tf + (size_t)b * T_ * K_;
  float val;
  if (r >= SEG_ - OVL_ && s <= 28) {
    float dec = (float)(SEG_ - r) * (1.f / (float)OVL_);
    float inc = (float)(r - (SEG_ - OVL_ - 1)) * (1.f / (float)OVL_);
    float v1 = sigval(tfb, s * 1100 + r);
    float v2 = sigval(tfb, (s + 1) * 1100 + (r - (SEG_ - OVL_)));
    val = dec * v1 + inc * v2;
  } else {
    val = sigval(tfb, s * 1100 + r);
  }
  outf[(size_t)b * OUTF_STRIDE_ + p] = f2b(val);
}

// ---------------------------------------------------------------------------
extern "C" void kernel_launch(void* const* d_in, const int* in_sizes, int n_in,
                              void* d_out, int out_size, void* d_ws, size_t ws_size,
                              hipStream_t stream) {
  const float* x = (const float*)d_in[0];
  char* ws = (char*)d_ws;
  float* synwin = (float*)(ws + SYNWIN_B);
  float* hann   = (float*)(ws + HANN_B);
  u16* BA   = (u16*)(ws + BASA_B);
  u16* BB   = (u16*)(ws + BASB_B);
  u16* Abuf = (u16*)(ws + ABUF_B);
  u16* TF   = (u16*)(ws + TF_B);
  u16* outf = (u16*)(ws + OUTF_B);

  hipLaunchKernelGGL(k1_tables, dim3(4), dim3(256), 0, stream, (float*)ws);
  hipLaunchKernelGGL(gen_basisA, dim3(1024), dim3(256), 0, stream, synwin, BA);
  hipLaunchKernelGGL(gen_basisB, dim3(512), dim3(256), 0, stream, hann, BB);
  hipLaunchKernelGGL(prep1, dim3(16, 3, 256), dim3(256), 0, stream, x, Abuf);
  hipLaunchKernelGGL((gemm_bf16<0>), dim3(NMA_PAD * 8), dim3(256), 0, stream,
                     Abuf, BA, (void*)TF);
  int n3 = B_ * OUT_LEN_;
  hipLaunchKernelGGL(k3_fold, dim3((n3 + 255) / 256), dim3(256), 0, stream, TF, outf);
  hipLaunchKernelGGL((gemm_bf16<1>), dim3(NMB_PAD * 8), dim3(256), 0, stream,
                     outf, BB, (void*)d_out);
}

// Round 4
// 332.972 us; speedup vs baseline: 1.0941x; 1.0941x over previous
//
#include <hip/hip_runtime.h>
#include <math.h>

typedef unsigned short u16;
typedef unsigned int u32;

#define B_   256
#define F_   512
#define T_   81
#define WIN_ 1022
#define HOP_ 400
#define NF_  69
#define OUT_LEN_ 28550
#define SEG_ 1000
#define OVL_ 50

#define MA_  20736     // B_*T_
#define MB_  17664     // B_*NF_
#define K_   1024
#define NMA_TILES 162  // MA_/128
#define NMB_TILES 138  // MB_/128
#define NMA_PAD   168  // next multiple of 8
#define NMB_PAD   144

// workspace byte offsets
#define BASA_B     0u                         // 1024*1024 bf16 = 2 MiB
#define BASB_B     (BASA_B + 2097152u)
#define ABUF_B     (BASB_B + 2097152u)        // 20736*1024 bf16
#define TF_B       (ABUF_B + 42467328u)       // 20736*1024 bf16
#define OUTF_B     (TF_B + 42467328u)         // 256*28672 bf16
#define OUTF_STRIDE_ 28672

typedef __attribute__((ext_vector_type(8))) short bf8_t;
typedef __attribute__((ext_vector_type(4))) float f4_t;
typedef const __attribute__((address_space(1))) void* as1cv;
typedef __attribute__((address_space(3))) void* as3v;

__device__ __forceinline__ float b2f(u16 v) {
  u32 u = ((u32)v) << 16; float f; __builtin_memcpy(&f, &u, 4); return f;
}
__device__ __forceinline__ u16 f2b(float f) {
  u32 u; __builtin_memcpy(&u, &f, 4);
  return (u16)((u + 0x7fffu + ((u >> 16) & 1u)) >> 16);
}

// ---------------------------------------------------------------------------
// BasisA[n][2k+j]: iDFT basis, transposed (n-major), synwin/N and c_k folded.
// Synthesis window computed inline (hann/denom with HOP=400 overlap of 3).
// ---------------------------------------------------------------------------
__global__ __launch_bounds__(256) void gen_basisA(u16* __restrict__ BA) {
  int n = blockIdx.x;                 // 0..1023
  const float twopi_N = 6.283185307179586f / (float)WIN_;
  float scale = 0.f;
  if (n < WIN_) {
    float w = 0.5f - 0.5f * cosf(twopi_N * (float)n);
    int j = n % HOP_;
    float a = 0.5f - 0.5f * cosf(twopi_N * (float)j);
    float b = 0.5f - 0.5f * cosf(twopi_N * (float)(j + 400));
    float d = a * a + b * b;
    if (j + 800 < WIN_) {
      float c2 = 0.5f - 0.5f * cosf(twopi_N * (float)(j + 800));
      d += c2 * c2;
    }
    scale = (w / d) * (1.0f / (float)WIN_);
  }
  for (int k = threadIdx.x; k < 512; k += 256) {
    int m = (k * n) % WIN_;
    float ang = twopi_N * (float)m;
    float s, c; __sincosf(ang, &s, &c);
    bool edge = (k == 0) || (k == 511);
    float ck = edge ? 1.f : 2.f;
    float re = scale * ck * c;
    float im = edge ? 0.f : -scale * ck * s;
    BA[(size_t)n * K_ + 2 * k]     = f2b(re);
    BA[(size_t)n * K_ + 2 * k + 1] = f2b(im);
  }
}

// ---------------------------------------------------------------------------
// BasisB[2k+j][w]: forward DFT basis, transposed, hann folded; 0 for w>=1022
// so GEMM B reads its A-operand straight from outf (2 garbage cols killed).
// ---------------------------------------------------------------------------
__global__ __launch_bounds__(256) void gen_basisB(u16* __restrict__ BB) {
  int k = blockIdx.x;                 // 0..511
  const float twopi_N = 6.283185307179586f / (float)WIN_;
  for (int w = threadIdx.x; w < K_; w += 256) {
    float re = 0.f, im = 0.f;
    if (w < WIN_) {
      int m = (k * w) % WIN_;
      float ang = twopi_N * (float)m;
      float s, c; __sincosf(ang, &s, &c);
      float h = 0.5f - 0.5f * cosf(twopi_N * (float)w);
      re = h * c; im = -h * s;
    }
    BB[(size_t)(2 * k)     * K_ + w] = f2b(re);
    BB[(size_t)(2 * k + 1) * K_ + w] = f2b(im);
  }
}

// ---------------------------------------------------------------------------
// prep1: x[b][k][t][2] fp32 -> Abuf[b*81+t][2k+j] bf16 (LDS-tiled transpose)
// ---------------------------------------------------------------------------
__global__ __launch_bounds__(256) void prep1(const float* __restrict__ x,
                                             u16* __restrict__ Abuf) {
  __shared__ float2 tile[32][33];
  int k0 = blockIdx.x * 32, t0 = blockIdx.y * 32, b = blockIdx.z;
  int c = threadIdx.x & 31, rr = threadIdx.x >> 5;
  const float2* xp = (const float2*)x;
#pragma unroll
  for (int i = 0; i < 4; ++i) {
    int k = k0 + rr + 8 * i, t = t0 + c;
    float2 v = make_float2(0.f, 0.f);
    if (t < T_) v = xp[(size_t)(b * F_ + k) * T_ + t];
    tile[rr + 8 * i][c] = v;
  }
  __syncthreads();
#pragma unroll
  for (int i = 0; i < 4; ++i) {
    int t = t0 + rr + 8 * i, kc = c;
    if (t < T_) {
      float2 v = tile[kc][rr + 8 * i];
      u32 packed = (u32)f2b(v.x) | ((u32)f2b(v.y) << 16);
      *(u32*)&Abuf[(size_t)(b * T_ + t) * K_ + 2 * (k0 + kc)] = packed;
    }
  }
}

// ---------------------------------------------------------------------------
// GEMM: C[M x 1024] = A[M x 1024] * Bt[1024 x 1024]^T  (Bt stored n-major)
// 128x128 tile, 4 waves (2x2 of 64x64), mfma 16x16x32 bf16, BK=32,
// DOUBLE-BUFFERED LDS: prefetch tile k+1 (global_load_lds width-16) into the
// alternate buffer before computing tile k; the single end-of-iter
// __syncthreads (compiler emits vmcnt(0) drain) is overlapped by compute.
// LDS layout is FRAGMENT-ORDERED (lane l's fragment at byte l*16): staging
// write and ds_read_b128 fragment read both sequential -> no bank conflicts.
// Grid XCD-swizzled: the 8 N-tiles of one M-strip land on one XCD.
// EPI 0: A from dense rows (stride K_), store bf16 C.
// EPI 1: A read directly from outf (row m=b*69+f at b*28672+f*400, stride
//        400), LDS-repack epilogue, float2 scatter to d_out.
// ---------------------------------------------------------------------------
template <int EPI>
__global__ __launch_bounds__(256) void gemm_bf16(const u16* __restrict__ A,
                                                 const u16* __restrict__ Bt,
                                                 void* __restrict__ Cout) {
  __shared__ u16 sA[2][4096];
  __shared__ u16 sB[2][4096];
  const int tid = threadIdx.x;
  const int lane = tid & 63, wv = tid >> 6;

  int id = blockIdx.x;
  int xcd = id & 7, slot = id >> 3;
  int mt = (slot >> 3) * 8 + xcd;
  int nt = slot & 7;
  const int nM = (EPI == 0) ? NMA_TILES : NMB_TILES;
  if (mt >= nM) return;
  const int bm = mt * 128, bn = nt * 128;

  const int fr = lane & 15, fq = lane >> 4;
  const int s0 = 2 * wv, s1 = s0 + 1;

  const u16 *pA0, *pA1;
  if (EPI == 0) {
    pA0 = A + (size_t)(bm + 16 * s0 + fr) * K_ + fq * 8;
    pA1 = A + (size_t)(bm + 16 * s1 + fr) * K_ + fq * 8;
  } else {
    int m0 = bm + 16 * s0 + fr;
    int b0 = m0 / NF_, f0 = m0 - b0 * NF_;
    pA0 = A + (size_t)b0 * OUTF_STRIDE_ + f0 * HOP_ + fq * 8;
    int m1 = m0 + 16;
    int b1 = m1 / NF_, f1 = m1 - b1 * NF_;
    pA1 = A + (size_t)b1 * OUTF_STRIDE_ + f1 * HOP_ + fq * 8;
  }
  const u16* pB0 = Bt + (size_t)(bn + 16 * s0 + fr) * K_ + fq * 8;
  const u16* pB1 = Bt + (size_t)(bn + 16 * s1 + fr) * K_ + fq * 8;

  f4_t acc[4][4];
#pragma unroll
  for (int i = 0; i < 4; ++i)
#pragma unroll
    for (int j = 0; j < 4; ++j) acc[i][j] = (f4_t){0.f, 0.f, 0.f, 0.f};

  const int wm4 = (wv >> 1) * 4, wn4 = (wv & 1) * 4;   // subtile bases

  // prologue: stage tile k=0 into buffer 0
  __builtin_amdgcn_global_load_lds((as1cv)(const void*)pA0, (as3v)(sA[0] + s0 * 512), 16, 0, 0);
  __builtin_amdgcn_global_load_lds((as1cv)(const void*)pA1, (as3v)(sA[0] + s1 * 512), 16, 0, 0);
  __builtin_amdgcn_global_load_lds((as1cv)(const void*)pB0, (as3v)(sB[0] + s0 * 512), 16, 0, 0);
  __builtin_amdgcn_global_load_lds((as1cv)(const void*)pB1, (as3v)(sB[0] + s1 * 512), 16, 0, 0);
  __builtin_amdgcn_s_waitcnt(0x0f70);  // vmcnt(0)
  __syncthreads();

  int cur = 0;
  for (int k0 = 0; k0 < K_; k0 += 32) {
    int nxt = k0 + 32;
    if (nxt < K_) {
      u16* dA = sA[cur ^ 1];
      u16* dB = sB[cur ^ 1];
      __builtin_amdgcn_global_load_lds((as1cv)(const void*)(pA0 + nxt), (as3v)(dA + s0 * 512), 16, 0, 0);
      __builtin_amdgcn_global_load_lds((as1cv)(const void*)(pA1 + nxt), (as3v)(dA + s1 * 512), 16, 0, 0);
      __builtin_amdgcn_global_load_lds((as1cv)(const void*)(pB0 + nxt), (as3v)(dB + s0 * 512), 16, 0, 0);
      __builtin_amdgcn_global_load_lds((as1cv)(const void*)(pB1 + nxt), (as3v)(dB + s1 * 512), 16, 0, 0);
    }

    const u16* cA = sA[cur];
    const u16* cB = sB[cur];
    bf8_t af[4], bq[4];
#pragma unroll
    for (int i = 0; i < 4; ++i)
      af[i] = *(const bf8_t*)&cA[(wm4 + i) * 512 + lane * 8];
#pragma unroll
    for (int j = 0; j < 4; ++j)
      bq[j] = *(const bf8_t*)&cB[(wn4 + j) * 512 + lane * 8];
#pragma unroll
    for (int i = 0; i < 4; ++i)
#pragma unroll
      for (int j = 0; j < 4; ++j)
        acc[i][j] = __builtin_amdgcn_mfma_f32_16x16x32_bf16(af[i], bq[j], acc[i][j], 0, 0, 0);

    __syncthreads();   // drains prefetch vmcnt + joins waves; overlapped by compute above
    cur ^= 1;
  }

  const int wm = wm4 * 16, wn = wn4 * 16;
  if (EPI == 0) {
    u16* C = (u16*)Cout;
#pragma unroll
    for (int i = 0; i < 4; ++i)
#pragma unroll
      for (int j = 0; j < 4; ++j) {
        int colg = bn + wn + 16 * j + fr;
#pragma unroll
        for (int r = 0; r < 4; ++r) {
          int rowg = bm + wm + 16 * i + fq * 4 + r;
          C[(size_t)rowg * K_ + colg] = f2b(acc[i][j][r]);
        }
      }
  } else {
    // per-wave LDS repack -> coalesced float2 scatter into out[b][k][f][2]
    float* out = (float*)Cout;
    float* ep = ((wv & 2) ? (float*)sB[0] : (float*)sA[0]) + (wv & 1) * 1024;  // 64x16 f32
    for (int j = 0; j < 4; ++j) {
#pragma unroll
      for (int i = 0; i < 4; ++i)
#pragma unroll
        for (int r = 0; r < 4; ++r) {
          int row64 = 16 * i + fq * 4 + r;
          ep[row64 * 16 + fr] = acc[i][j][r];
        }
      __syncthreads();
      int m = bm + wm + lane;          // frame index
      int b = m / NF_;
      int f = m - b * NF_;
      int colbase = bn + wn + 16 * j;  // even
#pragma unroll
      for (int a = 0; a < 8; ++a) {
        int k = (colbase >> 1) + a;
        float2 v = make_float2(ep[lane * 16 + 2 * a], ep[lane * 16 + 2 * a + 1]);
        ((float2*)out)[((size_t)b * F_ + k) * NF_ + f] = v;
      }
      __syncthreads();
    }
  }
}

// ---------------------------------------------------------------------------
// fold: overlap-add gather + keep + crossfade (bf16 in / bf16 out)
// ---------------------------------------------------------------------------
__device__ __forceinline__ float sigval(const u16* __restrict__ tfb, int i) {
  int t1 = i / HOP_; if (t1 > T_ - 1) t1 = T_ - 1;
  int t0 = (i >= WIN_) ? (i - (WIN_ - 1) + HOP_ - 1) / HOP_ : 0;
  float acc = 0.f;
  for (int t = t0; t <= t1; ++t)
    acc += b2f(tfb[(size_t)t * K_ + (i - t * HOP_)]);
  return acc;
}

__global__ __launch_bounds__(256) void k3_fold(const u16* __restrict__ tf,
                                               u16* __restrict__ outf) {
  int id = blockIdx.x * 256 + threadIdx.x;
  if (id >= B_ * OUT_LEN_) return;
  int b = id / OUT_LEN_;
  int p = id - b * OUT_LEN_;
  int s, r;
  if (p < SEG_) { s = 0; r = p; }
  else {
    int q = p - SEG_;
    s = q / (SEG_ - OVL_) + 1;
    r = OVL_ + (q - (s - 1) * (SEG_ - OVL_));
  }
  const u16* tfb = tf + (size_t)b * T_ * K_;
  float val;
  if (r >= SEG_ - OVL_ && s <= 28) {
    float dec = (float)(SEG_ - r) * (1.f / (float)OVL_);
    float inc = (float)(r - (SEG_ - OVL_ - 1)) * (1.f / (float)OVL_);
    float v1 = sigval(tfb, s * 1100 + r);
    float v2 = sigval(tfb, (s + 1) * 1100 + (r - (SEG_ - OVL_)));
    val = dec * v1 + inc * v2;
  } else {
    val = sigval(tfb, s * 1100 + r);
  }
  outf[(size_t)b * OUTF_STRIDE_ + p] = f2b(val);
}

// ---------------------------------------------------------------------------
extern "C" void kernel_launch(void* const* d_in, const int* in_sizes, int n_in,
                              void* d_out, int out_size, void* d_ws, size_t ws_size,
                              hipStream_t stream) {
  const float* x = (const float*)d_in[0];
  char* ws = (char*)d_ws;
  u16* BA   = (u16*)(ws + BASA_B);
  u16* BB   = (u16*)(ws + BASB_B);
  u16* Abuf = (u16*)(ws + ABUF_B);
  u16* TF   = (u16*)(ws + TF_B);
  u16* outf = (u16*)(ws + OUTF_B);

  hipLaunchKernelGGL(gen_basisA, dim3(1024), dim3(256), 0, stream, BA);
  hipLaunchKernelGGL(gen_basisB, dim3(512), dim3(256), 0, stream, BB);
  hipLaunchKernelGGL(prep1, dim3(16, 3, 256), dim3(256), 0, stream, x, Abuf);
  hipLaunchKernelGGL((gemm_bf16<0>), dim3(NMA_PAD * 8), dim3(256), 0, stream,
                     Abuf, BA, (void*)TF);
  int n3 = B_ * OUT_LEN_;
  hipLaunchKernelGGL(k3_fold, dim3((n3 + 255) / 256), dim3(256), 0, stream, TF, outf);
  hipLaunchKernelGGL((gemm_bf16<1>), dim3(NMB_PAD * 8), dim3(256), 0, stream,
                     outf, BB, (void*)d_out);
}